// Round 1
// baseline (786.320 us; speedup 1.0000x reference)
//
#include <hip/hip_runtime.h>
#include <cstdint>
#include <cstddef>

typedef _Float16 half8 __attribute__((ext_vector_type(8)));
typedef float floatx4 __attribute__((ext_vector_type(4)));

#define BATCH 256
#define NCHK 512
#define NVAR 1024
#define EDGE 3072

// ---- check MLP tiling ----
#define KC    96     // gemm1 K (96 message cols; sgn handled via w96 epilogue term)
#define NT1C  26     // hidden 388 -> 416 cols -> 26 n-tiles
#define KS1C  3      // 96/32
#define KS2C  13     // hidden padded 416 -> 13 k-steps
#define NT2C  6      // out 96 -> 6 n-tiles
#define HSTR_C 424   // LDS row stride (halves): 416 + 8 pad (16B-aligned rows, bank spread)

// ---- var MLP tiling ----
#define NT1V  13     // hidden 196 -> 208 -> 13 n-tiles
#define KS1V  2      // K 49 -> 64 -> 2 k-steps (prior at k=48)
#define KS2V  7      // hidden padded 224 -> 7 k-steps
#define NT2V  4      // out 49 -> 64 -> 4 n-tiles
#define HSTR_V 232   // 224 + 8 pad

__device__ __forceinline__ float gelu_f(float x) {
  // exact gelu via A&S 7.1.26 erf approx, |err(erf)| < 1.5e-7
  float ax = fabsf(x) * 0.70710678118654752440f;
  float t  = 1.0f / (1.0f + 0.3275911f * ax);
  float p  = t * (0.254829592f + t * (-0.284496736f + t * (1.421413741f +
             t * (-1.453152027f + t * 1.061405429f))));
  float e  = __expf(-ax * ax);
  float erfv = 1.0f - p * e;
  float s  = (x >= 0.0f) ? erfv : -erfv;
  return 0.5f * x * (1.0f + s);
}

// Pack weights fp32->fp16 into MFMA B-fragment-major layout:
// frag[(s*NT + nt)*64 + lane][j] = W[k = s*32 + (lane>>4)*8 + j][n = nt*16 + (lane&15)]
__global__ void pack_kernel(const float* __restrict__ cW1, const float* __restrict__ cb1,
                            const float* __restrict__ cW2, const float* __restrict__ cb2,
                            const float* __restrict__ vW1, const float* __restrict__ vb1,
                            const float* __restrict__ vW2, const float* __restrict__ vb2,
                            _Float16* __restrict__ w1c, _Float16* __restrict__ w2c,
                            _Float16* __restrict__ w1v, _Float16* __restrict__ w2v,
                            float* __restrict__ b1c, float* __restrict__ w96c,
                            float* __restrict__ b2c, float* __restrict__ b1v,
                            float* __restrict__ b2v)
{
  int id = blockIdx.x * 256 + threadIdx.x;
  const int S0 = KS1C * NT1C * 64;   // 4992
  const int S1 = KS2C * NT2C * 64;   // 4992
  const int S2 = KS1V * NT1V * 64;   // 1664
  const int S3 = KS2V * NT2V * 64;   // 1792
  if (id < S0) {
    int s = id / (NT1C * 64), rem = id % (NT1C * 64), nt = rem / 64, l = rem % 64;
    int q = l >> 4, n = nt * 16 + (l & 15);
    half8 v;
    #pragma unroll
    for (int j = 0; j < 8; ++j) {
      int k = s * 32 + q * 8 + j;                        // k < 96 always
      float x = (n < 388) ? cW1[k * 388 + n] : 0.0f;
      v[j] = (_Float16)x;
    }
    *(half8*)(w1c + (size_t)id * 8) = v;
    return;
  }
  id -= S0;
  if (id < S1) {
    int s = id / (NT2C * 64), rem = id % (NT2C * 64), nt = rem / 64, l = rem % 64;
    int q = l >> 4, n = nt * 16 + (l & 15);              // n < 96
    half8 v;
    #pragma unroll
    for (int j = 0; j < 8; ++j) {
      int k = s * 32 + q * 8 + j;                        // k < 416
      float x = (k < 388) ? cW2[k * 96 + n] : 0.0f;
      v[j] = (_Float16)x;
    }
    *(half8*)(w2c + (size_t)id * 8) = v;
    return;
  }
  id -= S1;
  if (id < S2) {
    int s = id / (NT1V * 64), rem = id % (NT1V * 64), nt = rem / 64, l = rem % 64;
    int q = l >> 4, n = nt * 16 + (l & 15);              // n < 208
    half8 v;
    #pragma unroll
    for (int j = 0; j < 8; ++j) {
      int k = s * 32 + q * 8 + j;                        // k < 64 ; row 48 = prior row
      float x = (k < 49 && n < 196) ? vW1[k * 196 + n] : 0.0f;
      v[j] = (_Float16)x;
    }
    *(half8*)(w1v + (size_t)id * 8) = v;
    return;
  }
  id -= S2;
  if (id < S3) {
    int s = id / (NT2V * 64), rem = id % (NT2V * 64), nt = rem / 64, l = rem % 64;
    int q = l >> 4, n = nt * 16 + (l & 15);              // n < 64
    half8 v;
    #pragma unroll
    for (int j = 0; j < 8; ++j) {
      int k = s * 32 + q * 8 + j;                        // k < 224
      float x = (k < 196 && n < 49) ? vW2[k * 49 + n] : 0.0f;
      v[j] = (_Float16)x;
    }
    *(half8*)(w2v + (size_t)id * 8) = v;
    return;
  }
  id -= S3;
  if (id < 416) { b1c[id]  = (id < 388) ? cb1[id] : 0.0f; return; }
  id -= 416;
  if (id < 416) { w96c[id] = (id < 388) ? cW1[96 * 388 + id] : 0.0f; return; }
  id -= 416;
  if (id < 96)  { b2c[id]  = cb2[id]; return; }
  id -= 96;
  if (id < 208) { b1v[id]  = (id < 196) ? vb1[id] : 0.0f; return; }
  id -= 208;
  if (id < 64)  { b2v[id]  = (id < 49) ? vb2[id] : 0.0f; return; }
}

// Mc0[b][perm[k]][0] = prior[k/3], all other channels 0. perm is a permutation -> full cover.
__global__ void init_kernel(const int* __restrict__ perm, const float* __restrict__ prior,
                            _Float16* __restrict__ Mc)
{
  int t = blockIdx.x * 256 + threadIdx.x;   // t < BATCH*EDGE
  int b = t / EDGE, k = t - b * EDGE;
  int e = perm[k];
  _Float16* dst = Mc + ((size_t)b * EDGE + e) * 16;
  half8 z  = {0,0,0,0,0,0,0,0};
  half8 z0 = z;
  z0[0] = (_Float16)prior[k / 3];
  *(half8*)dst = z0;
  *(half8*)(dst + 8) = z;
}

// Check-node MLP: rows = (b, chk). Mc (fp16, contiguous) -> Yc (fp16, contiguous)
__global__ __launch_bounds__(256) void kernelC(
    const _Float16* __restrict__ Mc, const int* __restrict__ synd,
    _Float16* __restrict__ Yc,
    const _Float16* __restrict__ W1p, const _Float16* __restrict__ W2p,
    const float* __restrict__ b1, const float* __restrict__ w96,
    const float* __restrict__ b2)
{
  __shared__ _Float16 HL[64 * HSTR_C];
  const int tid = threadIdx.x, w = tid >> 6, l = tid & 63;
  const int q = l >> 4, col = l & 15;
  const int r0 = blockIdx.x * 64 + w * 16;

  // A fragments for GEMM1 (K=96): lane holds row (r0+col), k = s*32 + q*8 + j
  const half8* Arow = (const half8*)(Mc + (size_t)(r0 + col) * KC);
  half8 a0 = Arow[q];
  half8 a1 = Arow[4 + q];
  half8 a2 = Arow[8 + q];

  // sgn for the epilogue rows this lane owns (row = r0 + q*4 + r)
  float sg[4];
  #pragma unroll
  for (int r = 0; r < 4; ++r) sg[r] = 1.0f - 2.0f * (float)synd[r0 + q * 4 + r];

  _Float16* Hw = HL + (size_t)(w * 16) * HSTR_C;
  const half8* W1f = (const half8*)W1p;
  #pragma unroll 2
  for (int nt = 0; nt < NT1C; ++nt) {
    floatx4 acc = {0.f, 0.f, 0.f, 0.f};
    half8 bb0 = W1f[(0 * NT1C + nt) * 64 + l];
    half8 bb1 = W1f[(1 * NT1C + nt) * 64 + l];
    half8 bb2 = W1f[(2 * NT1C + nt) * 64 + l];
    acc = __builtin_amdgcn_mfma_f32_16x16x32_f16(a0, bb0, acc, 0, 0, 0);
    acc = __builtin_amdgcn_mfma_f32_16x16x32_f16(a1, bb1, acc, 0, 0, 0);
    acc = __builtin_amdgcn_mfma_f32_16x16x32_f16(a2, bb2, acc, 0, 0, 0);
    const int n = nt * 16 + col;
    const float bias = b1[n], wsg = w96[n];
    #pragma unroll
    for (int r = 0; r < 4; ++r) {
      float y = acc[r] + bias + sg[r] * wsg;
      Hw[(q * 4 + r) * HSTR_C + n] = (_Float16)gelu_f(y);
    }
  }

  // GEMM2: K=416 from LDS (own wave's rows -> no barrier), N=96
  floatx4 acc2[NT2C];
  #pragma unroll
  for (int i = 0; i < NT2C; ++i) acc2[i] = (floatx4){0.f, 0.f, 0.f, 0.f};
  const _Float16* Ha = HL + (size_t)(w * 16 + col) * HSTR_C;
  const half8* W2f = (const half8*)W2p;
  #pragma unroll
  for (int s = 0; s < KS2C; ++s) {
    half8 a = *(const half8*)(Ha + s * 32 + q * 8);
    #pragma unroll
    for (int nt = 0; nt < NT2C; ++nt) {
      half8 bb = W2f[(s * NT2C + nt) * 64 + l];
      acc2[nt] = __builtin_amdgcn_mfma_f32_16x16x32_f16(a, bb, acc2[nt], 0, 0, 0);
    }
  }
  #pragma unroll
  for (int nt = 0; nt < NT2C; ++nt) {
    const int n = nt * 16 + col;
    const float bias = b2[n];
    #pragma unroll
    for (int r = 0; r < 4; ++r) {
      float y = (acc2[nt][r] + bias) * sg[r];
      Yc[(size_t)(r0 + q * 4 + r) * 96 + n] = (_Float16)y;
    }
  }
}

// Variable-node MLP: rows = (b, var). Gathers Yc via perm, scatters Mc via perm, emits llr.
__global__ __launch_bounds__(256) void kernelV(
    const _Float16* __restrict__ Yc, const int* __restrict__ perm,
    const float* __restrict__ prior,
    _Float16* __restrict__ Mc, float* __restrict__ outp,
    const _Float16* __restrict__ W1p, const _Float16* __restrict__ W2p,
    const float* __restrict__ b1, const float* __restrict__ b2)
{
  __shared__ _Float16 HL[64 * HSTR_V];
  const int tid = threadIdx.x, w = tid >> 6, l = tid & 63;
  const int q = l >> 4, col = l & 15;
  const int r0 = blockIdx.x * 64 + w * 16;
  const int rowA = r0 + col;
  const int bA = rowA >> 10, vA = rowA & 1023;

  // zero H pad cols [208,224) for this wave's rows (8B per lane)
  {
    uint64_t* z = (uint64_t*)(HL + (size_t)(w * 16 + col) * HSTR_V + 208 + q * 4);
    *z = 0ull;
  }

  // A fragments (K padded to 64): k<48 gathered from Yc, k=48 = prior, rest 0
  const size_t ybase = (size_t)bA * EDGE;
  int pe0 = perm[3 * vA + (q >> 1)];
  half8 a0 = *(const half8*)(Yc + (ybase + pe0) * 16 + (q & 1) * 8);
  half8 a1;
  if (q < 2) {
    int pe = perm[3 * vA + 2];
    a1 = *(const half8*)(Yc + (ybase + pe) * 16 + q * 8);
  } else if (q == 2) {
    half8 z = {0,0,0,0,0,0,0,0};
    z[0] = (_Float16)prior[vA];
    a1 = z;
  } else {
    a1 = (half8){0,0,0,0,0,0,0,0};
  }

  _Float16* Hw = HL + (size_t)(w * 16) * HSTR_V;
  const half8* W1f = (const half8*)W1p;
  #pragma unroll 2
  for (int nt = 0; nt < NT1V; ++nt) {
    floatx4 acc = {0.f, 0.f, 0.f, 0.f};
    half8 bb0 = W1f[(0 * NT1V + nt) * 64 + l];
    half8 bb1 = W1f[(1 * NT1V + nt) * 64 + l];
    acc = __builtin_amdgcn_mfma_f32_16x16x32_f16(a0, bb0, acc, 0, 0, 0);
    acc = __builtin_amdgcn_mfma_f32_16x16x32_f16(a1, bb1, acc, 0, 0, 0);
    const int n = nt * 16 + col;
    const float bias = b1[n];
    #pragma unroll
    for (int r = 0; r < 4; ++r) {
      float y = acc[r] + bias;
      Hw[(q * 4 + r) * HSTR_V + n] = (_Float16)gelu_f(y);
    }
  }

  floatx4 acc2[NT2V];
  #pragma unroll
  for (int i = 0; i < NT2V; ++i) acc2[i] = (floatx4){0.f, 0.f, 0.f, 0.f};
  const _Float16* Ha = HL + (size_t)(w * 16 + col) * HSTR_V;
  const half8* W2f = (const half8*)W2p;
  #pragma unroll
  for (int s = 0; s < KS2V; ++s) {
    half8 a = *(const half8*)(Ha + s * 32 + q * 8);
    #pragma unroll
    for (int nt = 0; nt < NT2V; ++nt) {
      half8 bb = W2f[(s * NT2V + nt) * 64 + l];
      acc2[nt] = __builtin_amdgcn_mfma_f32_16x16x32_f16(a, bb, acc2[nt], 0, 0, 0);
    }
  }
  #pragma unroll
  for (int nt = 0; nt < NT2V; ++nt) {
    const int n = nt * 16 + col;
    const float bias = b2[n];
    #pragma unroll
    for (int r = 0; r < 4; ++r) {
      float y = acc2[nt][r] + bias;
      int row = r0 + q * 4 + r;
      int b = row >> 10, v = row & 1023;
      if (n < 48) {
        int pe = perm[3 * v + nt];                     // n/16 == nt for n<48
        Mc[((size_t)b * EDGE + pe) * 16 + (n & 15)] = (_Float16)y;
      } else if (n == 48) {
        outp[row] = y;                                 // llr
      }
    }
  }
}

extern "C" void kernel_launch(void* const* d_in, const int* in_sizes, int n_in,
                              void* d_out, int out_size, void* d_ws, size_t ws_size,
                              hipStream_t stream)
{
  const int*   synd  = (const int*)d_in[0];
  // d_in[1] = num_iters (device scalar); T derived from out_size instead (no sync allowed)
  const float* prior = (const float*)d_in[2];
  const int*   perm  = (const int*)d_in[3];
  const float* cW1 = (const float*)d_in[4];
  const float* cb1 = (const float*)d_in[5];
  const float* cW2 = (const float*)d_in[6];
  const float* cb2 = (const float*)d_in[7];
  const float* vW1 = (const float*)d_in[8];
  const float* vb1 = (const float*)d_in[9];
  const float* vW2 = (const float*)d_in[10];
  const float* vb2 = (const float*)d_in[11];
  float* outp = (float*)d_out;
  const int T = out_size / (BATCH * NVAR);

  char* p = (char*)d_ws;
  _Float16* Mc  = (_Float16*)p; p += (size_t)BATCH * EDGE * 16 * 2;   // 25.2 MB
  _Float16* Yc  = (_Float16*)p; p += (size_t)BATCH * EDGE * 16 * 2;   // 25.2 MB
  _Float16* w1c = (_Float16*)p; p += (size_t)KS1C * NT1C * 64 * 8 * 2;
  _Float16* w2c = (_Float16*)p; p += (size_t)KS2C * NT2C * 64 * 8 * 2;
  _Float16* w1v = (_Float16*)p; p += (size_t)KS1V * NT1V * 64 * 8 * 2;
  _Float16* w2v = (_Float16*)p; p += (size_t)KS2V * NT2V * 64 * 8 * 2;
  float* b1c  = (float*)p; p += 416 * 4;
  float* w96c = (float*)p; p += 416 * 4;
  float* b2c  = (float*)p; p += 96 * 4;
  float* b1v  = (float*)p; p += 208 * 4;
  float* b2v  = (float*)p; p += 64 * 4;

  pack_kernel<<<(14640 + 255) / 256, 256, 0, stream>>>(
      cW1, cb1, cW2, cb2, vW1, vb1, vW2, vb2,
      w1c, w2c, w1v, w2v, b1c, w96c, b2c, b1v, b2v);
  init_kernel<<<(BATCH * EDGE) / 256, 256, 0, stream>>>(perm, prior, Mc);

  for (int t = 0; t < T; ++t) {
    kernelC<<<(BATCH * NCHK) / 64, 256, 0, stream>>>(
        Mc, synd, Yc, w1c, w2c, b1c, w96c, b2c);
    kernelV<<<(BATCH * NVAR) / 64, 256, 0, stream>>>(
        Yc, perm, prior, Mc, outp + (size_t)t * BATCH * NVAR, w1v, w2v, b1v, b2v);
  }
}

// Round 2
// 728.557 us; speedup vs baseline: 1.0793x; 1.0793x over previous
//
#include <hip/hip_runtime.h>
#include <cstdint>
#include <cstddef>

typedef _Float16 half8 __attribute__((ext_vector_type(8)));
typedef _Float16 half4 __attribute__((ext_vector_type(4)));
typedef float floatx4 __attribute__((ext_vector_type(4)));

#define BATCH 256
#define NCHK 512
#define NVAR 1024
#define EDGE 3072

// ---- check MLP tiling ----
#define KC    96
#define NT1C  26     // hidden 388 -> 416 -> 26 col-tiles
#define KS1C  3      // 96/32
#define SC_C  13     // 13 chunks of 32 hidden
#define NT2C  6      // out 96 -> 6 tiles
// ---- var MLP tiling ----
#define NT1V  13     // hidden 196 -> 208 -> 13 col-tiles
#define KS1V  2      // K 49 -> 64
#define SC_V  7      // GEMM2 K padded 224 -> 7 chunks of 32
#define NT2V  4      // out 49 -> 64 -> 4 tiles

#define HSTR 40      // LDS chunk row stride in halves (80 B: 16B-aligned, 2-way banks only)

__device__ __forceinline__ float gelu_f(float x) {
  // exact gelu via A&S 7.1.26 erf approx, |err(erf)| < 1.5e-7
  float ax = fabsf(x) * 0.70710678118654752440f;
  float t  = 1.0f / (1.0f + 0.3275911f * ax);
  float p  = t * (0.254829592f + t * (-0.284496736f + t * (1.421413741f +
             t * (-1.453152027f + t * 1.061405429f))));
  float e  = __expf(-ax * ax);
  float erfv = 1.0f - p * e;
  float s  = (x >= 0.0f) ? erfv : -erfv;
  return 0.5f * x * (1.0f + s);
}

// Pack weights fp32->fp16 into MFMA fragment-major layout (identical for A- or
// B-operand roles since per-lane layouts match):
// frag[(s*NT + nt)*64 + lane][j] = W[k = s*32 + (lane>>4)*8 + j][n = nt*16 + (lane&15)]
__global__ void pack_kernel(const float* __restrict__ cW1, const float* __restrict__ cb1,
                            const float* __restrict__ cW2, const float* __restrict__ cb2,
                            const float* __restrict__ vW1, const float* __restrict__ vb1,
                            const float* __restrict__ vW2, const float* __restrict__ vb2,
                            _Float16* __restrict__ w1c, _Float16* __restrict__ w2c,
                            _Float16* __restrict__ w1v, _Float16* __restrict__ w2v,
                            float* __restrict__ b1c, float* __restrict__ w96c,
                            float* __restrict__ b2c, float* __restrict__ b1v,
                            float* __restrict__ b2v)
{
  int id = blockIdx.x * 256 + threadIdx.x;
  const int S0 = KS1C * NT1C * 64;   // 4992
  const int S1 = SC_C * NT2C * 64;   // 4992
  const int S2 = KS1V * NT1V * 64;   // 1664
  const int S3 = SC_V * NT2V * 64;   // 1792
  if (id < S0) {
    int s = id / (NT1C * 64), rem = id % (NT1C * 64), nt = rem / 64, l = rem % 64;
    int q = l >> 4, n = nt * 16 + (l & 15);
    half8 v;
    #pragma unroll
    for (int j = 0; j < 8; ++j) {
      int k = s * 32 + q * 8 + j;
      float x = (n < 388) ? cW1[k * 388 + n] : 0.0f;
      v[j] = (_Float16)x;
    }
    *(half8*)(w1c + (size_t)id * 8) = v;
    return;
  }
  id -= S0;
  if (id < S1) {
    int s = id / (NT2C * 64), rem = id % (NT2C * 64), nt = rem / 64, l = rem % 64;
    int q = l >> 4, n = nt * 16 + (l & 15);
    half8 v;
    #pragma unroll
    for (int j = 0; j < 8; ++j) {
      int k = s * 32 + q * 8 + j;
      float x = (k < 388) ? cW2[k * 96 + n] : 0.0f;
      v[j] = (_Float16)x;
    }
    *(half8*)(w2c + (size_t)id * 8) = v;
    return;
  }
  id -= S1;
  if (id < S2) {
    int s = id / (NT1V * 64), rem = id % (NT1V * 64), nt = rem / 64, l = rem % 64;
    int q = l >> 4, n = nt * 16 + (l & 15);
    half8 v;
    #pragma unroll
    for (int j = 0; j < 8; ++j) {
      int k = s * 32 + q * 8 + j;                        // row 48 = prior row
      float x = (k < 49 && n < 196) ? vW1[k * 196 + n] : 0.0f;
      v[j] = (_Float16)x;
    }
    *(half8*)(w1v + (size_t)id * 8) = v;
    return;
  }
  id -= S2;
  if (id < S3) {
    int s = id / (NT2V * 64), rem = id % (NT2V * 64), nt = rem / 64, l = rem % 64;
    int q = l >> 4, n = nt * 16 + (l & 15);
    half8 v;
    #pragma unroll
    for (int j = 0; j < 8; ++j) {
      int k = s * 32 + q * 8 + j;
      float x = (k < 196 && n < 49) ? vW2[k * 49 + n] : 0.0f;
      v[j] = (_Float16)x;
    }
    *(half8*)(w2v + (size_t)id * 8) = v;
    return;
  }
  id -= S3;
  if (id < 416) { b1c[id]  = (id < 388) ? cb1[id] : 0.0f; return; }
  id -= 416;
  if (id < 416) { w96c[id] = (id < 388) ? cW1[96 * 388 + id] : 0.0f; return; }
  id -= 416;
  if (id < 96)  { b2c[id]  = cb2[id]; return; }
  id -= 96;
  if (id < 208) { b1v[id]  = (id < 196) ? vb1[id] : 0.0f; return; }
  id -= 208;
  if (id < 64)  { b2v[id]  = (id < 49) ? vb2[id] : 0.0f; return; }
}

__global__ void init_kernel(const int* __restrict__ perm, const float* __restrict__ prior,
                            _Float16* __restrict__ Mc)
{
  int t = blockIdx.x * 256 + threadIdx.x;   // t < BATCH*EDGE
  int b = t / EDGE, k = t - b * EDGE;
  int e = perm[k];
  _Float16* dst = Mc + ((size_t)b * EDGE + e) * 16;
  half8 z  = {0,0,0,0,0,0,0,0};
  half8 z0 = z;
  z0[0] = (_Float16)prior[k / 3];
  *(half8*)dst = z0;
  *(half8*)(dst + 8) = z;
}

// Check-node MLP, M=64 rows/wave, transposed GEMMs (H kept as H^T chunks in LDS).
// GEMM1': mfma(W1frag, Mcfrag) -> D[hid][row]; lane: row = l&15, hid = q*4+r.
// GEMM2': mfma(W2frag, Hfrag)  -> D[out][row]; lane: row = l&15, out = q*4+r.
__global__ __launch_bounds__(256, 2) void kernelC(
    const _Float16* __restrict__ Mc, const int* __restrict__ synd,
    _Float16* __restrict__ Yc,
    const _Float16* __restrict__ W1p, const _Float16* __restrict__ W2p,
    const float* __restrict__ b1, const float* __restrict__ w96,
    const float* __restrict__ b2)
{
  __shared__ _Float16 HL[4][2][64 * HSTR];   // 40 KiB
  const int tid = threadIdx.x, w = tid >> 6, l = tid & 63;
  const int q = l >> 4, c = l & 15;
  const int r0 = blockIdx.x * 256 + w * 64;

  // Mc fragments (B-operand: lane holds batch-row n = l&15, k = q*8+j)
  half8 mb[4][3];
  float sg[4];
  #pragma unroll
  for (int rg = 0; rg < 4; ++rg) {
    const _Float16* Arow = Mc + (size_t)(r0 + rg * 16 + c) * KC;
    #pragma unroll
    for (int ks = 0; ks < 3; ++ks)
      mb[rg][ks] = *(const half8*)(Arow + ks * 32 + q * 8);
    sg[rg] = 1.0f - 2.0f * (float)synd[r0 + rg * 16 + c];
  }

  floatx4 acc2[4][6];
  #pragma unroll
  for (int rg = 0; rg < 4; ++rg)
    #pragma unroll
    for (int nt = 0; nt < 6; ++nt)
      acc2[rg][nt] = (floatx4){0.f, 0.f, 0.f, 0.f};

  const half8* W1f = (const half8*)W1p;
  const half8* W2f = (const half8*)W2p;

  #pragma unroll 2
  for (int s = 0; s < SC_C; ++s) {
    _Float16* Hb = &HL[w][s & 1][0];
    #pragma unroll
    for (int u = 0; u < 2; ++u) {
      const int nt = s * 2 + u;
      half8 wa0 = W1f[(0 * NT1C + nt) * 64 + l];
      half8 wa1 = W1f[(1 * NT1C + nt) * 64 + l];
      half8 wa2 = W1f[(2 * NT1C + nt) * 64 + l];
      floatx4 bia = *(const floatx4*)(b1  + nt * 16 + q * 4);
      floatx4 wsg = *(const floatx4*)(w96 + nt * 16 + q * 4);
      #pragma unroll
      for (int rg = 0; rg < 4; ++rg) {
        floatx4 a = {0.f, 0.f, 0.f, 0.f};
        a = __builtin_amdgcn_mfma_f32_16x16x32_f16(wa0, mb[rg][0], a, 0, 0, 0);
        a = __builtin_amdgcn_mfma_f32_16x16x32_f16(wa1, mb[rg][1], a, 0, 0, 0);
        a = __builtin_amdgcn_mfma_f32_16x16x32_f16(wa2, mb[rg][2], a, 0, 0, 0);
        half4 hh;
        #pragma unroll
        for (int r = 0; r < 4; ++r)
          hh[r] = (_Float16)gelu_f(a[r] + bia[r] + sg[rg] * wsg[r]);
        *(half4*)(Hb + (rg * 16 + c) * HSTR + u * 16 + q * 4) = hh;
      }
    }
    half8 hf[4];
    #pragma unroll
    for (int rg = 0; rg < 4; ++rg)
      hf[rg] = *(const half8*)(Hb + (rg * 16 + c) * HSTR + q * 8);
    #pragma unroll
    for (int nt = 0; nt < 6; ++nt) {
      half8 wb = W2f[(s * NT2C + nt) * 64 + l];
      #pragma unroll
      for (int rg = 0; rg < 4; ++rg)
        acc2[rg][nt] = __builtin_amdgcn_mfma_f32_16x16x32_f16(wb, hf[rg], acc2[rg][nt], 0, 0, 0);
    }
  }

  #pragma unroll
  for (int rg = 0; rg < 4; ++rg) {
    const size_t row = (size_t)(r0 + rg * 16 + c);
    #pragma unroll
    for (int nt = 0; nt < 6; ++nt) {
      floatx4 bia = *(const floatx4*)(b2 + nt * 16 + q * 4);
      half4 yy;
      #pragma unroll
      for (int r = 0; r < 4; ++r)
        yy[r] = (_Float16)((acc2[rg][nt][r] + bia[r]) * sg[rg]);
      *(half4*)(Yc + row * 96 + nt * 16 + q * 4) = yy;
    }
  }
}

// Variable-node MLP, same transposed structure. Gathers Yc via perm (B-frags),
// scatters Mc via perm in packed 8B chunks, emits llr (out col 48).
__global__ __launch_bounds__(256, 2) void kernelV(
    const _Float16* __restrict__ Yc, const int* __restrict__ perm,
    const float* __restrict__ prior,
    _Float16* __restrict__ Mc, float* __restrict__ outp,
    const _Float16* __restrict__ W1p, const _Float16* __restrict__ W2p,
    const float* __restrict__ b1, const float* __restrict__ b2)
{
  __shared__ _Float16 HL[4][2][64 * HSTR];
  const int tid = threadIdx.x, w = tid >> 6, l = tid & 63;
  const int q = l >> 4, c = l & 15;
  const int r0 = blockIdx.x * 256 + w * 64;
  const int b  = r0 >> 10;
  const int v0 = r0 & 1023;
  const size_t yb = (size_t)b * EDGE;

  // Xv^T fragments: lane holds var-row n = l&15, k = q*8+j (K=64: 48 msgs + prior + pad)
  half8 mb[4][2];
  #pragma unroll
  for (int rg = 0; rg < 4; ++rg) {
    int v = v0 + rg * 16 + c;
    int e0 = perm[3 * v + (q >> 1)];
    mb[rg][0] = *(const half8*)(Yc + (yb + e0) * 16 + (q & 1) * 8);
    half8 m1 = {0,0,0,0,0,0,0,0};
    if (q < 2) {
      int e2 = perm[3 * v + 2];
      m1 = *(const half8*)(Yc + (yb + e2) * 16 + q * 8);
    } else if (q == 2) {
      m1[0] = (_Float16)prior[v];
    }
    mb[rg][1] = m1;
  }

  floatx4 acc2[4][4];
  #pragma unroll
  for (int rg = 0; rg < 4; ++rg)
    #pragma unroll
    for (int nt = 0; nt < 4; ++nt)
      acc2[rg][nt] = (floatx4){0.f, 0.f, 0.f, 0.f};

  const half8* W1f = (const half8*)W1p;
  const half8* W2f = (const half8*)W2p;

  #pragma unroll 2
  for (int s = 0; s < SC_V; ++s) {
    _Float16* Hb = &HL[w][s & 1][0];
    #pragma unroll
    for (int u = 0; u < 2; ++u) {
      const int nt = s * 2 + u;
      if (nt < NT1V) {
        half8 wa0 = W1f[(0 * NT1V + nt) * 64 + l];
        half8 wa1 = W1f[(1 * NT1V + nt) * 64 + l];
        floatx4 bia = *(const floatx4*)(b1 + nt * 16 + q * 4);
        #pragma unroll
        for (int rg = 0; rg < 4; ++rg) {
          floatx4 a = {0.f, 0.f, 0.f, 0.f};
          a = __builtin_amdgcn_mfma_f32_16x16x32_f16(wa0, mb[rg][0], a, 0, 0, 0);
          a = __builtin_amdgcn_mfma_f32_16x16x32_f16(wa1, mb[rg][1], a, 0, 0, 0);
          half4 hh;
          #pragma unroll
          for (int r = 0; r < 4; ++r)
            hh[r] = (_Float16)gelu_f(a[r] + bia[r]);
          *(half4*)(Hb + (rg * 16 + c) * HSTR + u * 16 + q * 4) = hh;
        }
      } else {
        half4 hz = {0,0,0,0};
        #pragma unroll
        for (int rg = 0; rg < 4; ++rg)
          *(half4*)(Hb + (rg * 16 + c) * HSTR + u * 16 + q * 4) = hz;
      }
    }
    half8 hf[4];
    #pragma unroll
    for (int rg = 0; rg < 4; ++rg)
      hf[rg] = *(const half8*)(Hb + (rg * 16 + c) * HSTR + q * 8);
    #pragma unroll
    for (int nt = 0; nt < 4; ++nt) {
      half8 wb = W2f[(s * NT2V + nt) * 64 + l];
      #pragma unroll
      for (int rg = 0; rg < 4; ++rg)
        acc2[rg][nt] = __builtin_amdgcn_mfma_f32_16x16x32_f16(wb, hf[rg], acc2[rg][nt], 0, 0, 0);
    }
  }

  const float bllr = b2[48];
  #pragma unroll
  for (int rg = 0; rg < 4; ++rg) {
    int v = v0 + rg * 16 + c;
    #pragma unroll
    for (int nt = 0; nt < 3; ++nt) {
      int pe = perm[3 * v + nt];
      floatx4 bia = *(const floatx4*)(b2 + nt * 16 + q * 4);
      half4 yy;
      #pragma unroll
      for (int r = 0; r < 4; ++r)
        yy[r] = (_Float16)(acc2[rg][nt][r] + bia[r]);
      *(half4*)(Mc + (yb + pe) * 16 + q * 4) = yy;
    }
    if (q == 0)
      outp[r0 + rg * 16 + c] = acc2[rg][3][0] + bllr;
  }
}

extern "C" void kernel_launch(void* const* d_in, const int* in_sizes, int n_in,
                              void* d_out, int out_size, void* d_ws, size_t ws_size,
                              hipStream_t stream)
{
  const int*   synd  = (const int*)d_in[0];
  const float* prior = (const float*)d_in[2];
  const int*   perm  = (const int*)d_in[3];
  const float* cW1 = (const float*)d_in[4];
  const float* cb1 = (const float*)d_in[5];
  const float* cW2 = (const float*)d_in[6];
  const float* cb2 = (const float*)d_in[7];
  const float* vW1 = (const float*)d_in[8];
  const float* vb1 = (const float*)d_in[9];
  const float* vW2 = (const float*)d_in[10];
  const float* vb2 = (const float*)d_in[11];
  float* outp = (float*)d_out;
  const int T = out_size / (BATCH * NVAR);

  char* p = (char*)d_ws;
  _Float16* Mc  = (_Float16*)p; p += (size_t)BATCH * EDGE * 16 * 2;
  _Float16* Yc  = (_Float16*)p; p += (size_t)BATCH * EDGE * 16 * 2;
  _Float16* w1c = (_Float16*)p; p += (size_t)KS1C * NT1C * 64 * 8 * 2;
  _Float16* w2c = (_Float16*)p; p += (size_t)SC_C * NT2C * 64 * 8 * 2;
  _Float16* w1v = (_Float16*)p; p += (size_t)KS1V * NT1V * 64 * 8 * 2;
  _Float16* w2v = (_Float16*)p; p += (size_t)SC_V * NT2V * 64 * 8 * 2;
  float* b1c  = (float*)p; p += 416 * 4;
  float* w96c = (float*)p; p += 416 * 4;
  float* b2c  = (float*)p; p += 96 * 4;
  float* b1v  = (float*)p; p += 208 * 4;
  float* b2v  = (float*)p; p += 64 * 4;

  pack_kernel<<<(14640 + 255) / 256, 256, 0, stream>>>(
      cW1, cb1, cW2, cb2, vW1, vb1, vW2, vb2,
      w1c, w2c, w1v, w2v, b1c, w96c, b2c, b1v, b2v);
  init_kernel<<<(BATCH * EDGE) / 256, 256, 0, stream>>>(perm, prior, Mc);

  for (int t = 0; t < T; ++t) {
    kernelC<<<(BATCH * NCHK) / 256, 256, 0, stream>>>(
        Mc, synd, Yc, w1c, w2c, b1c, w96c, b2c);
    kernelV<<<(BATCH * NVAR) / 256, 256, 0, stream>>>(
        Yc, perm, prior, Mc, outp + (size_t)t * BATCH * NVAR, w1v, w2v, b1v, b2v);
  }
}